// Round 2
// baseline (1080.805 us; speedup 1.0000x reference)
//
#include <hip/hip_runtime.h>
#include <hip/hip_bf16.h>
#include <math.h>

// VectorQuantizer: z (4,64,32,32,32) f32, embedding (1024,64) f32.
// Match the np/jax FP32 reference BIT-EXACTLY:
//   d_j = fl32( fl32(A + E_j) - 2*mm_j ),  A = pairwise8-sum(z_c^2),
//   E_j = pairwise8-sum(e_k^2), mm_j = serial-FMA dot (sgemm micro-kernel).
// argmin with lowest-index tie-break (np.argmin).
// Bulk pass uses a fast 4-chain dot (error ~4e-8 << grid ulp(64)=7.6e-6);
// rows whose quantized top-2 gap is within a few ulp are re-scored with the
// exact serial-FMA simulation. All replicating ops use __fadd_rn/__fmul_rn/
// fmaf so hipcc's fp-contraction cannot alter the arithmetic.

#define ENUM 1024
#define EDIM 64
#define SPAT 32768           // 32*32*32
#define NROWS 131072         // 4 * SPAT

// numpy pairwise_sum for n=64: 8 stride-8 accumulators, then tree combine.
__device__ __forceinline__ float pairwise64(const float* t) {
    float r[8];
#pragma unroll
    for (int l = 0; l < 8; ++l) r[l] = t[l];
#pragma unroll
    for (int i = 8; i < 64; i += 8) {
#pragma unroll
        for (int l = 0; l < 8; ++l) r[l] = __fadd_rn(r[l], t[i + l]);
    }
    return __fadd_rn(__fadd_rn(__fadd_rn(r[0], r[1]), __fadd_rn(r[2], r[3])),
                     __fadd_rn(__fadd_rn(r[4], r[5]), __fadd_rn(r[6], r[7])));
}

// ---------------------------------------------------------------- esq ------
__global__ __launch_bounds__(256) void vq_esq(const float* __restrict__ emb,
                                              float* __restrict__ esq) {
    int j = blockIdx.x * 256 + threadIdx.x;
    if (j >= ENUM) return;
    const float* e = emb + j * EDIM;
    float t[EDIM];
#pragma unroll
    for (int k = 0; k < EDIM; ++k) t[k] = __fmul_rn(e[k], e[k]);
    esq[j] = pairwise64(t);
}

// ------------------------------------------------------------- bulk --------
// One thread per row. Tracks quantized-simulated d; flags near-tie rows.
__global__ __launch_bounds__(256) void vq_bulk(const float* __restrict__ z,
                                               const float* __restrict__ emb,
                                               const float* __restrict__ esq,
                                               int* __restrict__ idx,
                                               float* __restrict__ flag) {
    int row = blockIdx.x * 256 + threadIdx.x;
    int b = row >> 15;
    int s = row & (SPAT - 1);
    const float* zb = z + (size_t)b * EDIM * SPAT + s;
    float zr[EDIM];
#pragma unroll
    for (int c = 0; c < EDIM; ++c) zr[c] = zb[(size_t)c * SPAT];  // coalesced per c

    float zsq[EDIM];
#pragma unroll
    for (int c = 0; c < EDIM; ++c) zsq[c] = __fmul_rn(zr[c], zr[c]);
    float A = pairwise64(zsq);   // bit-exact replica of sum(flat*flat, axis=1)

    float best = 3.4e38f, best2 = 3.4e38f;
    int bidx = 0;
    for (int j = 0; j < ENUM; ++j) {
        const float4* e4 = reinterpret_cast<const float4*>(emb + j * EDIM);
        float d0 = 0.f, d1 = 0.f, d2 = 0.f, d3 = 0.f;
#pragma unroll
        for (int k = 0; k < EDIM / 4; ++k) {
            float4 ev = e4[k];                  // wave-uniform -> s_load
            d0 = fmaf(zr[4 * k + 0], ev.x, d0);
            d1 = fmaf(zr[4 * k + 1], ev.y, d1);
            d2 = fmaf(zr[4 * k + 2], ev.z, d2);
            d3 = fmaf(zr[4 * k + 3], ev.w, d3);
        }
        float dot = (d0 + d1) + (d2 + d3);      // approx; assoc err ~4e-8 << ulp(64)
        float tmp = __fadd_rn(A, esq[j]);       // fl(A + E_j)
        float d = fmaf(-2.f, dot, tmp);         // fl(tmp - 2*dot), one rounding
        if (d < best) { best2 = best; best = d; bidx = j; }
        else if (d < best2) best2 = d;
    }
    idx[row] = bidx;
    // flag if quantized top-2 gap within ~5 ulp(best) (+slack): refine needed
    float thresh = fmaf(6e-7f, best, 4e-6f);
    flag[row] = (best2 - best) - thresh;        // <= 0 -> refine
}

// ------------------------------------------------------------ refine -------
// One wave per flagged row; lanes split the 1024 codes (j = lane + 64t,
// ascending within lane). EXACT fp32 simulation of the reference:
//   dot = serial single-accumulator fmaf chain (sgemm micro-kernel order).
// Lexicographic (d, j) reduction = np.argmin first-occurrence semantics.
__global__ __launch_bounds__(64) void vq_refine(const float* __restrict__ z,
                                                const float* __restrict__ emb,
                                                const float* __restrict__ esq,
                                                const float* __restrict__ flag,
                                                int* __restrict__ idx) {
    int lane = threadIdx.x;
    for (int row = blockIdx.x; row < NROWS; row += gridDim.x) {
        if (flag[row] > 0.f) continue;          // uniform branch
        int b = row >> 15;
        int s = row & (SPAT - 1);
        const float* zb = z + (size_t)b * EDIM * SPAT + s;
        float zr[EDIM];
#pragma unroll
        for (int c = 0; c < EDIM; ++c) zr[c] = zb[(size_t)c * SPAT];
        float zsq[EDIM];
#pragma unroll
        for (int c = 0; c < EDIM; ++c) zsq[c] = __fmul_rn(zr[c], zr[c]);
        float A = pairwise64(zsq);

        float bd = 3.4e38f;
        int bj = 0;
#pragma unroll 2
        for (int t = 0; t < ENUM / 64; ++t) {   // ascending j within lane
            int j = lane + 64 * t;
            const float* ej = emb + j * EDIM;
            float acc = 0.f;
#pragma unroll
            for (int k = 0; k < EDIM; ++k)
                acc = fmaf(zr[k], ej[k], acc);  // serial FMA, sgemm order
            float tmp = __fadd_rn(A, esq[j]);
            float d = fmaf(-2.f, acc, tmp);     // bit-exact reference d_j
            if (d < bd) { bd = d; bj = j; }     // strict < keeps lowest j
        }
#pragma unroll
        for (int off = 32; off > 0; off >>= 1) {
            float od = __shfl_down(bd, off, 64);
            int oj = __shfl_down(bj, off, 64);
            if (od < bd || (od == bd && oj < bj)) { bd = od; bj = oj; }
        }
        if (lane == 0) idx[row] = bj;
    }
}

// ------------------------------------------------------------ gather -------
__global__ __launch_bounds__(256) void vq_gather(const float* __restrict__ emb,
                                                 const int* __restrict__ idx,
                                                 float* __restrict__ out) {
    int row = blockIdx.x * 256 + threadIdx.x;
    int b = row >> 15;
    int s = row & (SPAT - 1);
    int j = idx[row];
    const float4* e4 = reinterpret_cast<const float4*>(emb + j * EDIM);
    float ev[EDIM];
#pragma unroll
    for (int k = 0; k < EDIM / 4; ++k) {
        float4 v = e4[k];
        ev[4 * k + 0] = v.x; ev[4 * k + 1] = v.y;
        ev[4 * k + 2] = v.z; ev[4 * k + 3] = v.w;
    }
    float* ob = out + (size_t)b * EDIM * SPAT + s;
#pragma unroll
    for (int c = 0; c < EDIM; ++c) ob[(size_t)c * SPAT] = ev[c];  // coalesced per c
}

// ------------------------------------------------------------ launch -------
extern "C" void kernel_launch(void* const* d_in, const int* in_sizes, int n_in,
                              void* d_out, int out_size, void* d_ws, size_t ws_size,
                              hipStream_t stream) {
    const float* z   = (const float*)d_in[0];
    const float* emb = (const float*)d_in[1];
    float* out = (float*)d_out;

    // ws layout: esq f32[1024] | idx i32[NROWS] | flag f32[NROWS]  (~1.05 MB)
    float* esq  = (float*)d_ws;
    int*   idx  = (int*)((char*)d_ws + 4096);
    float* flag = (float*)((char*)d_ws + 4096 + sizeof(int) * (size_t)NROWS);

    vq_esq   <<<ENUM / 256,  256, 0, stream>>>(emb, esq);
    vq_bulk  <<<NROWS / 256, 256, 0, stream>>>(z, emb, esq, idx, flag);
    vq_refine<<<2048,        64,  0, stream>>>(z, emb, esq, flag, idx);
    vq_gather<<<NROWS / 256, 256, 0, stream>>>(emb, idx, out);
}

// Round 3
// 653.350 us; speedup vs baseline: 1.6543x; 1.6543x over previous
//
#include <hip/hip_runtime.h>
#include <hip/hip_bf16.h>
#include <math.h>

// VectorQuantizer: z (4,64,32,32,32) f32, embedding (1024,64) f32.
// Match the np/jax FP32 reference BIT-EXACTLY:
//   d_j = fl32( fl32(A + E_j) - 2*mm_j ),  A = pairwise8-sum(z_c^2),
//   E_j = pairwise8-sum(e_k^2), mm_j = serial-FMA dot (sgemm micro-kernel).
// argmin with lowest-index tie-break (np.argmin).
// Bulk pass: fast 4-chain dot (assoc err ~4e-8 << ulp(64)=7.6e-6 grid of the
// reference's quantized distances); rows whose quantized top-2 gap is within
// ~5 ulp get re-scored with the exact serial-FMA simulation.
//
// R2 -> R3: bulk was latency-bound (VALUBusy 19%, VGPR=56 -> zr spilled,
// occupancy grid-limited at 2 waves/SIMD). Fix: __launch_bounds__(256,4)
// (VGPR cap 128, keep zr[64] resident) + 4-way codebook-segment split
// (8192 waves -> ~5 waves/SIMD) + combine kernel for cross-segment top-2.

#define ENUM 1024
#define EDIM 64
#define SPAT 32768           // 32*32*32
#define NROWS 131072         // 4 * SPAT
#define NSEG 4
#define JSEG (ENUM / NSEG)   // 256

// numpy pairwise_sum for n=64: 8 stride-8 accumulators, then tree combine.
__device__ __forceinline__ float pairwise64(const float* t) {
    float r[8];
#pragma unroll
    for (int l = 0; l < 8; ++l) r[l] = t[l];
#pragma unroll
    for (int i = 8; i < 64; i += 8) {
#pragma unroll
        for (int l = 0; l < 8; ++l) r[l] = __fadd_rn(r[l], t[i + l]);
    }
    return __fadd_rn(__fadd_rn(__fadd_rn(r[0], r[1]), __fadd_rn(r[2], r[3])),
                     __fadd_rn(__fadd_rn(r[4], r[5]), __fadd_rn(r[6], r[7])));
}

// ---------------------------------------------------------------- esq ------
__global__ __launch_bounds__(256) void vq_esq(const float* __restrict__ emb,
                                              float* __restrict__ esq) {
    int j = blockIdx.x * 256 + threadIdx.x;
    if (j >= ENUM) return;
    const float* e = emb + j * EDIM;
    float t[EDIM];
#pragma unroll
    for (int k = 0; k < EDIM; ++k) t[k] = __fmul_rn(e[k], e[k]);
    esq[j] = pairwise64(t);
}

// ------------------------------------------------------------- bulk --------
// One thread per (row, segment-of-256-codes). zr[64] register-resident.
__global__ __launch_bounds__(256, 4) void vq_bulk(const float* __restrict__ z,
                                                  const float* __restrict__ emb,
                                                  const float* __restrict__ esq,
                                                  float* __restrict__ pb,
                                                  float* __restrict__ pb2,
                                                  int* __restrict__ pj) {
    int row = blockIdx.x * 256 + threadIdx.x;
    int seg = blockIdx.y;
    int b = row >> 15;
    int s = row & (SPAT - 1);
    const float* zb = z + (size_t)b * EDIM * SPAT + s;
    float zr[EDIM];
#pragma unroll
    for (int c = 0; c < EDIM; ++c) zr[c] = zb[(size_t)c * SPAT];  // coalesced per c

    float zsq[EDIM];
#pragma unroll
    for (int c = 0; c < EDIM; ++c) zsq[c] = __fmul_rn(zr[c], zr[c]);
    float A = pairwise64(zsq);   // bit-exact replica of sum(flat*flat, axis=1)

    int jbeg = seg * JSEG, jend = jbeg + JSEG;
    float best = 3.4e38f, best2 = 3.4e38f;
    int bidx = jbeg;
    for (int j = jbeg; j < jend; ++j) {
        const float4* e4 = reinterpret_cast<const float4*>(emb + j * EDIM);
        float d0 = 0.f, d1 = 0.f, d2 = 0.f, d3 = 0.f;
#pragma unroll
        for (int k = 0; k < EDIM / 4; ++k) {
            float4 ev = e4[k];                  // wave-uniform -> scalar load
            d0 = fmaf(zr[4 * k + 0], ev.x, d0);
            d1 = fmaf(zr[4 * k + 1], ev.y, d1);
            d2 = fmaf(zr[4 * k + 2], ev.z, d2);
            d3 = fmaf(zr[4 * k + 3], ev.w, d3);
        }
        float dot = (d0 + d1) + (d2 + d3);      // approx; err << quantization grid
        float tmp = __fadd_rn(A, esq[j]);       // fl(A + E_j)
        float d = fmaf(-2.f, dot, tmp);         // fl(tmp - 2*dot), one rounding
        if (d < best) { best2 = best; best = d; bidx = j; }
        else if (d < best2) best2 = d;
    }
    pb [seg * NROWS + row] = best;
    pb2[seg * NROWS + row] = best2;
    pj [seg * NROWS + row] = bidx;
}

// ----------------------------------------------------------- combine -------
// Merge per-segment top-2 into global top-2; preserve first-occurrence ties.
__global__ __launch_bounds__(256) void vq_combine(const float* __restrict__ pb,
                                                  const float* __restrict__ pb2,
                                                  const int* __restrict__ pj,
                                                  int* __restrict__ idx,
                                                  float* __restrict__ flag) {
    int row = blockIdx.x * 256 + threadIdx.x;
    float best = 3.4e38f, best2 = 3.4e38f;
    int bidx = 0;
#pragma unroll
    for (int sg = 0; sg < NSEG; ++sg) {         // ascending seg = ascending j
        float bA = pb [sg * NROWS + row];
        float bB = pb2[sg * NROWS + row];
        int   jA = pj [sg * NROWS + row];
        if (bA < best) { best2 = fminf(best, bB); best = bA; bidx = jA; }
        else           { best2 = fminf(best2, bA); }
    }
    idx[row] = bidx;
    // flag if quantized top-2 gap within ~5 ulp(best) (+slack): refine needed
    float thresh = fmaf(6e-7f, best, 4e-6f);
    flag[row] = (best2 - best) - thresh;        // <= 0 -> refine
}

// ------------------------------------------------------------ refine -------
// One wave per flagged row; lanes split the 1024 codes (j = lane + 64t,
// ascending within lane). EXACT fp32 simulation of the reference:
//   dot = serial single-accumulator fmaf chain (sgemm micro-kernel order).
// Lexicographic (d, j) reduction = np.argmin first-occurrence semantics.
__global__ __launch_bounds__(64) void vq_refine(const float* __restrict__ z,
                                                const float* __restrict__ emb,
                                                const float* __restrict__ esq,
                                                const float* __restrict__ flag,
                                                int* __restrict__ idx) {
    int lane = threadIdx.x;
    for (int row = blockIdx.x; row < NROWS; row += gridDim.x) {
        if (flag[row] > 0.f) continue;          // uniform branch
        int b = row >> 15;
        int s = row & (SPAT - 1);
        const float* zb = z + (size_t)b * EDIM * SPAT + s;
        float zr[EDIM];
#pragma unroll
        for (int c = 0; c < EDIM; ++c) zr[c] = zb[(size_t)c * SPAT];
        float zsq[EDIM];
#pragma unroll
        for (int c = 0; c < EDIM; ++c) zsq[c] = __fmul_rn(zr[c], zr[c]);
        float A = pairwise64(zsq);

        float bd = 3.4e38f;
        int bj = 0;
#pragma unroll 2
        for (int t = 0; t < ENUM / 64; ++t) {   // ascending j within lane
            int j = lane + 64 * t;
            const float* ej = emb + j * EDIM;
            float acc = 0.f;
#pragma unroll
            for (int k = 0; k < EDIM; ++k)
                acc = fmaf(zr[k], ej[k], acc);  // serial FMA, sgemm order
            float tmp = __fadd_rn(A, esq[j]);
            float d = fmaf(-2.f, acc, tmp);     // bit-exact reference d_j
            if (d < bd) { bd = d; bj = j; }     // strict < keeps lowest j
        }
#pragma unroll
        for (int off = 32; off > 0; off >>= 1) {
            float od = __shfl_down(bd, off, 64);
            int oj = __shfl_down(bj, off, 64);
            if (od < bd || (od == bd && oj < bj)) { bd = od; bj = oj; }
        }
        if (lane == 0) idx[row] = bj;
    }
}

// ------------------------------------------------------------ gather -------
__global__ __launch_bounds__(256) void vq_gather(const float* __restrict__ emb,
                                                 const int* __restrict__ idx,
                                                 float* __restrict__ out) {
    int row = blockIdx.x * 256 + threadIdx.x;
    int b = row >> 15;
    int s = row & (SPAT - 1);
    int j = idx[row];
    const float4* e4 = reinterpret_cast<const float4*>(emb + j * EDIM);
    float ev[EDIM];
#pragma unroll
    for (int k = 0; k < EDIM / 4; ++k) {
        float4 v = e4[k];
        ev[4 * k + 0] = v.x; ev[4 * k + 1] = v.y;
        ev[4 * k + 2] = v.z; ev[4 * k + 3] = v.w;
    }
    float* ob = out + (size_t)b * EDIM * SPAT + s;
#pragma unroll
    for (int c = 0; c < EDIM; ++c) ob[(size_t)c * SPAT] = ev[c];  // coalesced per c
}

// ------------------------------------------------------------ launch -------
extern "C" void kernel_launch(void* const* d_in, const int* in_sizes, int n_in,
                              void* d_out, int out_size, void* d_ws, size_t ws_size,
                              hipStream_t stream) {
    const float* z   = (const float*)d_in[0];
    const float* emb = (const float*)d_in[1];
    float* out = (float*)d_out;

    // ws layout: esq f32[1024] (4KB pad) | pb f32[4][NROWS] | pb2 f32[4][NROWS]
    //            | pj i32[4][NROWS] | idx i32[NROWS] | flag f32[NROWS]  (~7.4 MB)
    char* w = (char*)d_ws;
    float* esq  = (float*)w;                                   w += 4096;
    float* pb   = (float*)w;  w += sizeof(float) * NSEG * (size_t)NROWS;
    float* pb2  = (float*)w;  w += sizeof(float) * NSEG * (size_t)NROWS;
    int*   pj   = (int*)w;    w += sizeof(int)   * NSEG * (size_t)NROWS;
    int*   idx  = (int*)w;    w += sizeof(int)   * (size_t)NROWS;
    float* flag = (float*)w;

    vq_esq    <<<ENUM / 256, 256, 0, stream>>>(emb, esq);
    dim3 bgrid(NROWS / 256, NSEG);
    vq_bulk   <<<bgrid,      256, 0, stream>>>(z, emb, esq, pb, pb2, pj);
    vq_combine<<<NROWS / 256, 256, 0, stream>>>(pb, pb2, pj, idx, flag);
    vq_refine <<<2048,        64, 0, stream>>>(z, emb, esq, flag, idx);
    vq_gather <<<NROWS / 256, 256, 0, stream>>>(emb, idx, out);
}

// Round 4
// 452.491 us; speedup vs baseline: 2.3886x; 1.4439x over previous
//
#include <hip/hip_runtime.h>
#include <hip/hip_bf16.h>
#include <math.h>

// VectorQuantizer: z (4,64,32,32,32) f32, embedding (1024,64) f32.
// R4: f16 MFMA prefilter (codebook pre-scaled x1024, whole codebook in LDS,
// fused best/best2/argmin epilogue) + provable per-row margin; flagged rows
// (~10%) re-scored by the bit-exact fp32 reference simulation (R2/R3-proven):
//   d_j = fl32( fl32(A + E_j) - 2*serialFMA(z,e_j) ), pairwise8 sums,
//   np.argmin lowest-index ties.

#define ENUM 1024
#define EDIM 64
#define SPAT 32768           // 32*32*32
#define NROWS 131072         // 4 * SPAT
#define LDS_STRIDE 72        // halves per code row: 64 data + 2 (esq f32) + pad; 144B, 16B-aligned

typedef _Float16 half8 __attribute__((ext_vector_type(8)));
typedef float f32x4 __attribute__((ext_vector_type(4)));
typedef unsigned short us8 __attribute__((ext_vector_type(8)));

// numpy pairwise_sum for n=64: 8 stride-8 accumulators, then tree combine.
__device__ __forceinline__ float pairwise64(const float* t) {
    float r[8];
#pragma unroll
    for (int l = 0; l < 8; ++l) r[l] = t[l];
#pragma unroll
    for (int i = 8; i < 64; i += 8) {
#pragma unroll
        for (int l = 0; l < 8; ++l) r[l] = __fadd_rn(r[l], t[i + l]);
    }
    return __fadd_rn(__fadd_rn(__fadd_rn(r[0], r[1]), __fadd_rn(r[2], r[3])),
                     __fadd_rn(__fadd_rn(r[4], r[5]), __fadd_rn(r[6], r[7])));
}

// ---------------------------------------------------------------- prep -----
// One block, 1024 threads: exact esq (ref pairwise replica), f16 codebook
// scaled x1024, max(esq) for the margin, zero the refine counter.
__global__ __launch_bounds__(1024) void vq_prep(const float* __restrict__ emb,
                                                float* __restrict__ esq_g,
                                                _Float16* __restrict__ ef,
                                                float* __restrict__ maxesq,
                                                unsigned int* __restrict__ cnt) {
    __shared__ float red[1024];
    int j = threadIdx.x;
    const float4* ep = reinterpret_cast<const float4*>(emb + j * EDIM);
    float t[EDIM];
#pragma unroll
    for (int kk = 0; kk < 16; ++kk) {
        float4 v = ep[kk];
        t[4 * kk + 0] = __fmul_rn(v.x, v.x);
        t[4 * kk + 1] = __fmul_rn(v.y, v.y);
        t[4 * kk + 2] = __fmul_rn(v.z, v.z);
        t[4 * kk + 3] = __fmul_rn(v.w, v.w);
        ef[j * EDIM + 4 * kk + 0] = (_Float16)(v.x * 1024.0f);
        ef[j * EDIM + 4 * kk + 1] = (_Float16)(v.y * 1024.0f);
        ef[j * EDIM + 4 * kk + 2] = (_Float16)(v.z * 1024.0f);
        ef[j * EDIM + 4 * kk + 3] = (_Float16)(v.w * 1024.0f);
    }
    float e2 = pairwise64(t);
    esq_g[j] = e2;
    red[j] = e2;
    __syncthreads();
    for (int s = 512; s > 0; s >>= 1) {
        if (j < s) red[j] = fmaxf(red[j], red[j + s]);
        __syncthreads();
    }
    if (j == 0) { *maxesq = red[0]; *cnt = 0u; }
}

// ------------------------------------------------------------- score -------
// 256 blocks x 1024 thr (16 waves). Whole codebook (f16, x1024) + esq in LDS.
// Each wave: 2 row-tiles of 16 rows; per row-tile iterate 64 col-tiles:
// 2x mfma_f32_16x16x32_f16 (K=64) + fused best/best2/argmin epilogue.
// A-frag: lane l -> row l%16, k = (l/16)*8 + i  (i=0..7 contiguous).
// B-frag: lane l -> col l%16, k = (l/16)*8 + i  -> e'[col][k] contiguous 16B.
// C:      lane l, reg q -> row (l/16)*4+q, col l%16  (m89-verified).
__global__ __launch_bounds__(1024, 4) void vq_score(const float* __restrict__ z,
                                                    const _Float16* __restrict__ ef,
                                                    const float* __restrict__ esq_g,
                                                    const float* __restrict__ maxesq,
                                                    int* __restrict__ idx,
                                                    int* __restrict__ list,
                                                    unsigned int* __restrict__ cnt) {
    __shared__ __align__(16) unsigned short eL[ENUM * LDS_STRIDE];  // 147456 B

    int tid = threadIdx.x;
    // ---- stage codebook + esq into LDS (code j = tid) ----
    {
        const unsigned short* src = reinterpret_cast<const unsigned short*>(ef) + tid * EDIM;
#pragma unroll
        for (int i = 0; i < 8; ++i)
            *reinterpret_cast<us8*>(&eL[tid * LDS_STRIDE + i * 8]) =
                *reinterpret_cast<const us8*>(src + i * 8);
        *reinterpret_cast<float*>(&eL[tid * LDS_STRIDE + 64]) = esq_g[tid];
    }
    __syncthreads();

    int l  = tid & 63;
    int w  = tid >> 6;          // wave 0..15
    int g  = l >> 4;            // k-group 0..3
    int li = l & 15;            // row (A) / col (B) within tile
    float mxe = *maxesq;

    for (int c = 0; c < 2; ++c) {
        int rt0 = blockIdx.x * 512 + w * 32 + c * 16;   // row-tile base
        int b = rt0 >> 15;
        int s0 = (rt0 & (SPAT - 1)) + li;
        const float* zp = z + (size_t)b * EDIM * SPAT + s0;
        int o = g * 8;

        float za[8], zb8[8];
#pragma unroll
        for (int i = 0; i < 8; ++i) za[i]  = zp[(size_t)(o + i) * SPAT];
#pragma unroll
        for (int i = 0; i < 8; ++i) zb8[i] = zp[(size_t)(32 + o + i) * SPAT];

        // ||z||^2 partial -> full (groups hold disjoint k-octets)
        float pa = 0.f;
#pragma unroll
        for (int i = 0; i < 8; ++i) pa += za[i] * za[i] + zb8[i] * zb8[i];
        pa += __shfl_xor(pa, 16);
        pa += __shfl_xor(pa, 32);

        half8 fa0, fa1;
#pragma unroll
        for (int i = 0; i < 8; ++i) { fa0[i] = (_Float16)za[i]; fa1[i] = (_Float16)zb8[i]; }

        // per-q sound margin: 2^-8 * sqrt(A*max||e||^2) + 3e-5
        float mrg[4];
#pragma unroll
        for (int q = 0; q < 4; ++q) {
            float Aq = __shfl(pa, g * 4 + q);
            mrg[q] = fmaf(sqrtf(Aq * mxe), 0.00390625f, 3.0e-5f);
        }

        float best[4], best2[4];
        int bidx[4];
#pragma unroll
        for (int q = 0; q < 4; ++q) { best[q] = 3.4e38f; best2[q] = 3.4e38f; bidx[q] = 0; }

        for (int ct = 0; ct < 64; ++ct) {
            int code = ct * 16 + li;
            int base = code * LDS_STRIDE + g * 8;
            half8 fb0 = *reinterpret_cast<const half8*>(&eL[base]);
            half8 fb1 = *reinterpret_cast<const half8*>(&eL[base + 32]);
            float esqv = *reinterpret_cast<const float*>(&eL[code * LDS_STRIDE + 64]);
            f32x4 acc = {0.f, 0.f, 0.f, 0.f};
            acc = __builtin_amdgcn_mfma_f32_16x16x32_f16(fa0, fb0, acc, 0, 0, 0);
            acc = __builtin_amdgcn_mfma_f32_16x16x32_f16(fa1, fb1, acc, 0, 0, 0);
#pragma unroll
            for (int q = 0; q < 4; ++q) {
                float sc = fmaf(-0.001953125f, acc[q], esqv);   // esq - 2^-9 * dot'
                bool lt = sc < best[q];
                best2[q] = fminf(best2[q], fmaxf(best[q], sc));
                best[q]  = fminf(best[q], sc);
                bidx[q]  = lt ? code : bidx[q];
            }
        }

        // merge across the 16 col-lanes of this row-group
#pragma unroll
        for (int off = 1; off < 16; off <<= 1) {
#pragma unroll
            for (int q = 0; q < 4; ++q) {
                float nb  = __shfl_xor(best[q], off);
                float nb2 = __shfl_xor(best2[q], off);
                int   nj  = __shfl_xor(bidx[q], off);
                best2[q] = fminf(fminf(best2[q], nb2), fmaxf(best[q], nb));
                bool tk = nb < best[q];
                best[q] = fminf(best[q], nb);
                bidx[q] = tk ? nj : bidx[q];
            }
        }

        if (li < 4) {
            int q = li;
            int row = rt0 + g * 4 + q;
            idx[row] = bidx[q];
            if (best2[q] - best[q] <= mrg[q]) {
                unsigned int p = atomicAdd(cnt, 1u);
                list[p] = row;
            }
        }
    }
}

// ------------------------------------------------------------ refine -------
// One wave per flagged row (compacted list). EXACT fp32 reference simulation
// (serial-FMA dot, pairwise A); lexicographic (d, j) = np.argmin semantics.
__global__ __launch_bounds__(64) void vq_refine(const float* __restrict__ z,
                                                const float* __restrict__ emb,
                                                const float* __restrict__ esq,
                                                const int* __restrict__ list,
                                                const unsigned int* __restrict__ cnt,
                                                int* __restrict__ idx) {
    int lane = threadIdx.x;
    unsigned int n = *cnt;
    for (unsigned int i = blockIdx.x; i < n; i += gridDim.x) {
        int row = list[i];
        int b = row >> 15;
        int s = row & (SPAT - 1);
        const float* zb = z + (size_t)b * EDIM * SPAT + s;
        float zr[EDIM];
#pragma unroll
        for (int c = 0; c < EDIM; ++c) zr[c] = zb[(size_t)c * SPAT];
        float zsq[EDIM];
#pragma unroll
        for (int c = 0; c < EDIM; ++c) zsq[c] = __fmul_rn(zr[c], zr[c]);
        float A = pairwise64(zsq);

        float bd = 3.4e38f;
        int bj = 0;
#pragma unroll 2
        for (int t = 0; t < ENUM / 64; ++t) {   // ascending j within lane
            int j = lane + 64 * t;
            const float* ej = emb + j * EDIM;
            float acc = 0.f;
#pragma unroll
            for (int k = 0; k < EDIM; ++k)
                acc = fmaf(zr[k], ej[k], acc);  // serial FMA, sgemm order
            float tmp = __fadd_rn(A, esq[j]);
            float d = fmaf(-2.f, acc, tmp);     // bit-exact reference d_j
            if (d < bd) { bd = d; bj = j; }     // strict < keeps lowest j
        }
#pragma unroll
        for (int off = 32; off > 0; off >>= 1) {
            float od = __shfl_down(bd, off, 64);
            int oj = __shfl_down(bj, off, 64);
            if (od < bd || (od == bd && oj < bj)) { bd = od; bj = oj; }
        }
        if (lane == 0) idx[row] = bj;
    }
}

// ------------------------------------------------------------ gather -------
__global__ __launch_bounds__(256) void vq_gather(const float* __restrict__ emb,
                                                 const int* __restrict__ idx,
                                                 float* __restrict__ out) {
    int row = blockIdx.x * 256 + threadIdx.x;
    int b = row >> 15;
    int s = row & (SPAT - 1);
    int j = idx[row];
    const float4* e4 = reinterpret_cast<const float4*>(emb + j * EDIM);
    float ev[EDIM];
#pragma unroll
    for (int k = 0; k < EDIM / 4; ++k) {
        float4 v = e4[k];
        ev[4 * k + 0] = v.x; ev[4 * k + 1] = v.y;
        ev[4 * k + 2] = v.z; ev[4 * k + 3] = v.w;
    }
    float* ob = out + (size_t)b * EDIM * SPAT + s;
#pragma unroll
    for (int c = 0; c < EDIM; ++c) ob[(size_t)c * SPAT] = ev[c];  // coalesced per c
}

// ------------------------------------------------------------ launch -------
extern "C" void kernel_launch(void* const* d_in, const int* in_sizes, int n_in,
                              void* d_out, int out_size, void* d_ws, size_t ws_size,
                              hipStream_t stream) {
    const float* z   = (const float*)d_in[0];
    const float* emb = (const float*)d_in[1];
    float* out = (float*)d_out;

    // ws: esq f32[1024] | maxesq f32 | cnt u32 (pad to 4KB) | ef f16[1024*64]
    //     | idx i32[NROWS] | list i32[NROWS]   (~1.16 MB)
    char* wp = (char*)d_ws;
    float* esq = (float*)wp;                       wp += 4096;
    float* mxe = (float*)wp;
    unsigned int* cnt = (unsigned int*)(wp + 16);  wp += 4096;
    _Float16* ef = (_Float16*)wp;                  wp += sizeof(_Float16) * ENUM * EDIM;
    int* idx = (int*)wp;                           wp += sizeof(int) * (size_t)NROWS;
    int* list = (int*)wp;

    vq_prep  <<<1,           1024, 0, stream>>>(emb, esq, ef, mxe, cnt);
    vq_score <<<256,         1024, 0, stream>>>(z, ef, esq, mxe, idx, list, cnt);
    vq_refine<<<2048,          64, 0, stream>>>(z, emb, esq, list, cnt, idx);
    vq_gather<<<NROWS / 256,  256, 0, stream>>>(emb, idx, out);
}